// Round 8
// baseline (117.835 us; speedup 1.0000x reference)
//
#include <hip/hip_runtime.h>

#define BLK 256
#define QPT 3                   // float4 per thread -> 3072-element capacity per block
#define CAPB (QPT * BLK * 4)    // 3072
#define CC 96                   // per-wave candidate segment (4 segments total)

// ---------- wave-local reductions (64-lane) ----------

__device__ __forceinline__ float wave_max(float v) {
#pragma unroll
  for (int o = 32; o; o >>= 1) v = fmaxf(v, __shfl_xor(v, o));
  return v;
}
__device__ __forceinline__ float wave_sum(float v) {
#pragma unroll
  for (int o = 32; o; o >>= 1) v += __shfl_xor(v, o);
  return v;
}
__device__ __forceinline__ int wave_sum_i(int v) {
#pragma unroll
  for (int o = 32; o; o >>= 1) v += __shfl_xor(v, o);
  return v;
}

__device__ __forceinline__ void block_sum_cnt(float& s, int& c, float* redf, int* redi, int tid) {
  s = wave_sum(s); c = wave_sum_i(c);
  __syncthreads();
  if ((tid & 63) == 0) { redf[tid >> 6] = s; redi[tid >> 6] = c; }
  __syncthreads();
  s = redf[0] + redf[1] + redf[2] + redf[3];
  c = redi[0] + redi[1] + redi[2] + redi[3];
}

// ---------- wave-parallel 65-ary lower_bound over sorted int32 keys ----------
__device__ __forceinline__ int wave_lower_bound(const int* __restrict__ batch, int N,
                                                int target, int lane) {
  int lo = 0, hi = N;
  while (hi > lo) {
    const long long span = hi - lo;
    const int m = lo + (int)((span * (long long)(lane + 1)) / 65);  // in [lo, hi-1]
    const int flag = (batch[m] < target) ? 1 : 0;
    const unsigned long long bal = __ballot(flag);
    const int c = __popcll(bal);
    int nlo = lo, nhi = hi;
    if (c > 0)  nlo = lo + (int)((span * (long long)c) / 65) + 1;
    if (c < 64) nhi = lo + (int)((span * (long long)(c + 1)) / 65);
    lo = nlo; hi = nhi;
  }
  return lo;
}

// ---------- kernel 1: one WAVE per boundary -> starts[0..B] ----------

extern "C" __global__ void __launch_bounds__(BLK)
build_starts_bs(const int* __restrict__ batch, int* __restrict__ starts,
                const int* __restrict__ pB, int N) {
  const int B = *pB;
  const int lane = threadIdx.x & 63;
  const int w    = threadIdx.x >> 6;
  const int wpg  = gridDim.x * (BLK / 64);
  for (int t = blockIdx.x * (BLK / 64) + w; t <= B; t += wpg) {
    int v;
    if (t == 0) v = 0;
    else if (t >= B) v = N;              // batch values are < B
    else v = wave_lower_bound(batch, N, t, lane);
    if (lane == 0) starts[t] = v;
  }
}

// ---------- kernel 2: one BLOCK per group, TWO barriers ----------
// Wave-local candidate bound: tau >= xmax-1 >= wavemax-1, so each wave
// compacts {x > wavemax-1} (raw values; the support condition is
// shift-invariant) into its own LDS segment -- no cross-wave max, no
// atomics, no init barrier. Then one barrier -> wave 0 exact solve
// (gather union, shfl rank-sort + prefix scan + ballot) -> one barrier
// -> store. Tiers: c<=64 exact; segments valid -> wave-0 Michelot;
// overflow -> block Michelot on registers (superset init tau <= tau*).

extern "C" __global__ void __launch_bounds__(BLK)
sparsemax_groups(const float* __restrict__ x, const int* __restrict__ starts,
                 const int* __restrict__ pB, float* __restrict__ out, int N) {
  __shared__ float cand[4][CC];
  __shared__ float csumS[4];
  __shared__ int   ccnt[4];
  __shared__ float sorted[64];
  __shared__ float redf[4];
  __shared__ int   redi[4];
  __shared__ float s_tau;
  const int tid  = threadIdx.x;
  const int lane = tid & 63;
  const int w    = tid >> 6;
  const int B = *pB;

  for (int g = blockIdx.x; g < B; g += gridDim.x) {
    const int s = starts[g];
    const int e = starts[g + 1];
    const int n = e - s;
    if (n <= 0) continue;                // block-uniform: barrier matching safe
    const int a0 = s & ~3;               // 16B-aligned load base

    if (e - a0 <= CAPB) {
      // ---- phase 1: aligned float4 global -> registers, wave-local max ----
      float4 r[QPT];
      float lmax = -INFINITY;
#pragma unroll
      for (int j = 0; j < QPT; ++j) {
        const int idx = a0 + (j * BLK + tid) * 4;
        float4 v;
        if (idx >= s && idx + 4 <= e) {          // interior quad: no masking
          v = *(const float4*)(x + idx);
        } else {
          v = make_float4(-INFINITY, -INFINITY, -INFINITY, -INFINITY);
          if (idx < e) {                          // boundary quad
            if (idx + 4 <= N) {
              v = *(const float4*)(x + idx);
            } else {                              // buffer tail (last group only)
              if (idx + 0 < N) v.x = x[idx + 0];
              if (idx + 1 < N) v.y = x[idx + 1];
              if (idx + 2 < N) v.z = x[idx + 2];
              if (idx + 3 < N) v.w = x[idx + 3];
            }
            if (idx + 0 < s || idx + 0 >= e) v.x = -INFINITY;  // mask other groups
            if (idx + 1 < s || idx + 1 >= e) v.y = -INFINITY;
            if (idx + 2 < s || idx + 2 >= e) v.z = -INFINITY;
            if (idx + 3 < s || idx + 3 >= e) v.w = -INFINITY;
          }
        }
        r[j] = v;
        lmax = fmaxf(lmax, fmaxf(fmaxf(v.x, v.y), fmaxf(v.z, v.w)));
      }
      lmax = wave_max(lmax);
      const float thr = lmax - 1.0f;     // wave-local bound (-inf for empty waves)

      // ---- phase 2: wave-local prefix-scan compaction into own segment ----
      int cm = 0; float ws = 0.0f;
#pragma unroll
      for (int j = 0; j < QPT; ++j) {
        const float vv[4] = {r[j].x, r[j].y, r[j].z, r[j].w};
#pragma unroll
        for (int t = 0; t < 4; ++t)
          if (vv[t] > thr) { cm++; ws += vv[t]; }   // raw values
      }
      int pfx = cm;                      // inclusive scan of counts
#pragma unroll
      for (int o = 1; o < 64; o <<= 1) {
        const int t2 = __shfl_up(pfx, o);
        if (lane >= o) pfx += t2;
      }
      int off = pfx - cm;                // exclusive offset in own segment
      if (cm > 0) {
#pragma unroll
        for (int j = 0; j < QPT; ++j) {
          const float vv[4] = {r[j].x, r[j].y, r[j].z, r[j].w};
#pragma unroll
          for (int t = 0; t < 4; ++t)
            if (vv[t] > thr) { if (off < CC) cand[w][off] = vv[t]; off++; }
        }
      }
      ws = wave_sum(ws);
      if (lane == 63) ccnt[w] = pfx;     // lane 63 holds wave total
      if (lane == 0)  csumS[w] = ws;
      __syncthreads();                   // barrier 1 (the ONLY pre-solve barrier)

      const int c0 = ccnt[0], c1 = ccnt[1], c2 = ccnt[2], c3 = ccnt[3];
      const int c = c0 + c1 + c2 + c3;   // >= 1 (wave holding xmax passes it)
      const int mxc = max(max(c0, c1), max(c2, c3));

      if (c <= 64) {
        if (w == 0) {                    // exact solve on wave 0
          float v = -INFINITY;
          if (lane < c) {                // gather union from 4 segments
            int o2 = lane, seg = 0;
            if (o2 >= c0) { o2 -= c0; seg = 1;
              if (o2 >= c1) { o2 -= c1; seg = 2;
                if (o2 >= c2) { o2 -= c2; seg = 3; } } }
            v = cand[seg][o2];
          }
          int rank = 0;                  // all-pairs rank via shfl broadcast
          for (int q = 0; q < c; ++q) {
            const float t = __shfl(v, q);
            rank += (t > v) || (t == v && q < lane);
          }
          if (lane < c) sorted[rank] = v;          // in-wave LDS: no barrier
          const float sv = (lane < c) ? sorted[lane] : 0.0f;
          float cs = sv;
#pragma unroll
          for (int o = 1; o < 64; o <<= 1) {       // inclusive prefix scan
            const float t2 = __shfl_up(cs, o);
            if (lane >= o) cs += t2;
          }
          const int flag = (lane < c) && (sv * (float)(lane + 1) > cs - 1.0f);
          const unsigned long long bal = __ballot(flag);   // lane 0 always true
          const int k = 63 - __clzll(bal);                 // support size - 1
          const float csk = __shfl(cs, k);
          if (lane == 0) s_tau = (csk - 1.0f) / (float)(k + 1);
        }
      } else if (mxc <= CC) {
        if (w == 0) {                    // wave-0 Michelot over LDS segments
          float tau = (csumS[0] + csumS[1] + csumS[2] + csumS[3] - 1.0f) / (float)c;
          int cnt = c;
          for (int it = 0; it < 64; ++it) {
            float s2 = 0.0f; int c2 = 0;
            for (int seg = 0; seg < 4; ++seg) {
              const int cc = ccnt[seg];
              for (int q = lane; q < cc; q += 64) {
                const float vv = cand[seg][q];
                if (vv > tau) { s2 += vv; c2++; }
              }
            }
            s2 = wave_sum(s2); c2 = wave_sum_i(c2);
            if (c2 == cnt || c2 == 0) break;
            tau = (s2 - 1.0f) / (float)c2; cnt = c2;
          }
          if (lane == 0) s_tau = tau;
        }
      } else {
        // segment overflow: block Michelot on registers, raw space.
        // init from candidate superset: tau0 = (sum_S - 1)/|S| <= tau*.
        float tau = (csumS[0] + csumS[1] + csumS[2] + csumS[3] - 1.0f) / (float)c;
        int cnt = c;
        for (int it = 0; it < 64; ++it) {
          float s2 = 0.0f; int c2 = 0;
#pragma unroll
          for (int j = 0; j < QPT; ++j) {
            const float vv[4] = {r[j].x, r[j].y, r[j].z, r[j].w};
#pragma unroll
            for (int t = 0; t < 4; ++t)
              if (vv[t] > tau) { s2 += vv[t]; c2++; }   // -inf never passes
          }
          block_sum_cnt(s2, c2, redf, redi, tid);
          if (c2 == cnt || c2 == 0) break;
          tau = (s2 - 1.0f) / (float)c2; cnt = c2;
        }
        if (tid == 0) s_tau = tau;
      }
      __syncthreads();                   // barrier 2
      const float sub = s_tau;           // raw-space threshold

      // ---- phase 3: store (vector interior, scalar boundary quads) ----
#pragma unroll
      for (int j = 0; j < QPT; ++j) {
        const int idx = a0 + (j * BLK + tid) * 4;
        if (idx >= e) continue;
        if (idx >= s && idx + 4 <= e) {
          float4 o4;
          o4.x = fmaxf(r[j].x - sub, 0.0f);
          o4.y = fmaxf(r[j].y - sub, 0.0f);
          o4.z = fmaxf(r[j].z - sub, 0.0f);
          o4.w = fmaxf(r[j].w - sub, 0.0f);
          *(float4*)(out + idx) = o4;
        } else {
          const float vv[4] = {r[j].x, r[j].y, r[j].z, r[j].w};
#pragma unroll
          for (int t = 0; t < 4; ++t) {
            const int p2 = idx + t;
            if (p2 >= s && p2 < e) out[p2] = fmaxf(vv[t] - sub, 0.0f);
          }
        }
      }
    } else {
      // ---- n > capacity fallback: block-strided global Michelot ----
      float gmax = -INFINITY;
      for (int i = s + tid; i < e; i += BLK) gmax = fmaxf(gmax, x[i]);
      gmax = wave_max(gmax);
      if (lane == 0) redf[w] = gmax;
      __syncthreads();
      gmax = fmaxf(fmaxf(redf[0], redf[1]), fmaxf(redf[2], redf[3]));
      float bs = 0.0f; int bc = 0;
      for (int i = s + tid; i < e; i += BLK) {
        const float vs = x[i] - gmax;
        if (vs > -1.0f) { bs += vs; bc++; }
      }
      block_sum_cnt(bs, bc, redf, redi, tid);
      float tau = (bs - 1.0f) / (float)bc;
      int cntS = bc;
      for (int it = 0; it < 64; ++it) {
        float s2 = 0.0f; int c2 = 0;
        for (int i = s + tid; i < e; i += BLK) {
          const float vs = x[i] - gmax;
          if (vs > tau) { s2 += vs; c2++; }
        }
        block_sum_cnt(s2, c2, redf, redi, tid);
        if (c2 == cntS || c2 == 0) break;
        tau = (s2 - 1.0f) / (float)c2; cntS = c2;
      }
      const float sub2 = tau + gmax;
      for (int i = s + tid; i < e; i += BLK) out[i] = fmaxf(x[i] - sub2, 0.0f);
    }
  }
}

extern "C" void kernel_launch(void* const* d_in, const int* in_sizes, int n_in,
                              void* d_out, int out_size, void* d_ws, size_t ws_size,
                              hipStream_t stream) {
  const float* x     = (const float*)d_in[0];
  const int*   batch = (const int*)d_in[1];   // int32 on device (JAX x64 disabled)
  const int*   pB    = (const int*)d_in[2];
  float*       out   = (float*)d_out;
  const int N = in_sizes[0];

  int* starts = (int*)d_ws;                    // 4*(B+1) bytes of scratch

  // kernel1: 1025 blocks x 4 waves = 4100 waves >= 4097 boundaries
  build_starts_bs<<<dim3(1025), dim3(BLK), 0, stream>>>(batch, starts, pB, N);
  // kernel2: one block per group; grid-strides if B > 4096
  sparsemax_groups<<<dim3(4096), dim3(BLK), 0, stream>>>(x, starts, pB, out, N);
}

// Round 9
// 115.432 us; speedup vs baseline: 1.0208x; 1.0208x over previous
//
#include <hip/hip_runtime.h>

#define BLK 256
#define QPT 3                   // float4 per thread -> 3072-element capacity per block
#define CAPB (QPT * BLK * 4)    // 3072
#define CCAP 320                // candidate buffer: c<=64 exact; <=CCAP wave Michelot; else block Michelot

// ---------- wave-local reductions (64-lane) ----------

__device__ __forceinline__ float wave_max(float v) {
#pragma unroll
  for (int o = 32; o; o >>= 1) v = fmaxf(v, __shfl_xor(v, o));
  return v;
}
__device__ __forceinline__ float wave_sum(float v) {
#pragma unroll
  for (int o = 32; o; o >>= 1) v += __shfl_xor(v, o);
  return v;
}
__device__ __forceinline__ int wave_sum_i(int v) {
#pragma unroll
  for (int o = 32; o; o >>= 1) v += __shfl_xor(v, o);
  return v;
}

__device__ __forceinline__ void block_sum_cnt(float& s, int& c, float* redf, int* redi, int tid) {
  s = wave_sum(s); c = wave_sum_i(c);
  __syncthreads();
  if ((tid & 63) == 0) { redf[tid >> 6] = s; redi[tid >> 6] = c; }
  __syncthreads();
  s = redf[0] + redf[1] + redf[2] + redf[3];
  c = redi[0] + redi[1] + redi[2] + redi[3];
}

// ---------- wave-parallel 65-ary lower_bound over sorted int32 keys ----------
__device__ __forceinline__ int wave_lower_bound(const int* __restrict__ batch, int N,
                                                int target, int lane) {
  int lo = 0, hi = N;
  while (hi > lo) {
    const long long span = hi - lo;
    const int m = lo + (int)((span * (long long)(lane + 1)) / 65);  // in [lo, hi-1]
    const int flag = (batch[m] < target) ? 1 : 0;
    const unsigned long long bal = __ballot(flag);
    const int c = __popcll(bal);
    int nlo = lo, nhi = hi;
    if (c > 0)  nlo = lo + (int)((span * (long long)c) / 65) + 1;
    if (c < 64) nhi = lo + (int)((span * (long long)(c + 1)) / 65);
    lo = nlo; hi = nhi;
  }
  return lo;
}

// ---------- kernel 1: one WAVE per boundary -> starts[0..B] ----------

extern "C" __global__ void __launch_bounds__(BLK)
build_starts_bs(const int* __restrict__ batch, int* __restrict__ starts,
                const int* __restrict__ pB, int N) {
  const int B = *pB;
  const int lane = threadIdx.x & 63;
  const int w    = threadIdx.x >> 6;
  const int wpg  = gridDim.x * (BLK / 64);
  for (int t = blockIdx.x * (BLK / 64) + w; t <= B; t += wpg) {
    int v;
    if (t == 0) v = 0;
    else if (t >= B) v = N;              // batch values are < B
    else v = wave_lower_bound(batch, N, t, lane);
    if (lane == 0) starts[t] = v;
  }
}

// ---------- kernel 2: one BLOCK per group, TWO barriers, redundant solve ----------
// tau >= xmax-1 (outputs sum to 1) => support subset of {x > gmax-1}.
// Ballot-compact raw values into LDS; after the compaction barrier EVERY
// wave runs the identical exact solve (shfl rank-sort + prefix scan +
// ballot) -> no result broadcast, no third barrier. Grid 2048 = 8 blocks/CU
// exactly; each block grid-strides 2 groups (no block retire between
// residency generations).

extern "C" __global__ void __launch_bounds__(BLK)
sparsemax_groups(const float* __restrict__ x, const int* __restrict__ starts,
                 const int* __restrict__ pB, float* __restrict__ out, int N) {
  __shared__ float cand[CCAP];
  __shared__ float sorted[4][64];
  __shared__ float redf[4];
  __shared__ int   redi[4];
  __shared__ int   s_cnt;
  __shared__ float s_tau;
  const int tid  = threadIdx.x;
  const int lane = tid & 63;
  const int w    = tid >> 6;
  const int B = *pB;

  for (int g = blockIdx.x; g < B; g += gridDim.x) {
    const int s = starts[g];
    const int e = starts[g + 1];
    const int n = e - s;
    if (n <= 0) continue;                // block-uniform: barrier matching safe
    const int a0 = s & ~3;               // 16B-aligned load base

    if (e - a0 <= CAPB) {
      // ---- phase 1: aligned float4 global -> registers, fused max ----
      float4 r[QPT];
      float lmax = -INFINITY;
#pragma unroll
      for (int j = 0; j < QPT; ++j) {
        const int idx = a0 + (j * BLK + tid) * 4;
        float4 v;
        if (idx >= s && idx + 4 <= e) {          // interior quad: no masking
          v = *(const float4*)(x + idx);
        } else {
          v = make_float4(-INFINITY, -INFINITY, -INFINITY, -INFINITY);
          if (idx < e) {                          // boundary quad
            if (idx + 4 <= N) {
              v = *(const float4*)(x + idx);
            } else {                              // buffer tail (last group only)
              if (idx + 0 < N) v.x = x[idx + 0];
              if (idx + 1 < N) v.y = x[idx + 1];
              if (idx + 2 < N) v.z = x[idx + 2];
              if (idx + 3 < N) v.w = x[idx + 3];
            }
            if (idx + 0 < s || idx + 0 >= e) v.x = -INFINITY;  // mask other groups
            if (idx + 1 < s || idx + 1 >= e) v.y = -INFINITY;
            if (idx + 2 < s || idx + 2 >= e) v.z = -INFINITY;
            if (idx + 3 < s || idx + 3 >= e) v.w = -INFINITY;
          }
        }
        r[j] = v;
        lmax = fmaxf(lmax, fmaxf(fmaxf(v.x, v.y), fmaxf(v.z, v.w)));
      }
      lmax = wave_max(lmax);
      if (lane == 0) redf[w] = lmax;
      if (tid == 0) s_cnt = 0;
      __syncthreads();                   // barrier 1
      const float gmax = fmaxf(fmaxf(redf[0], redf[1]), fmaxf(redf[2], redf[3]));
      const float thr = gmax - 1.0f;     // raw-space support bound (tau* >= thr)

      // ---- phase 2: ballot compaction of raw values ----
#pragma unroll
      for (int j = 0; j < QPT; ++j) {
        const float vv[4] = {r[j].x, r[j].y, r[j].z, r[j].w};
#pragma unroll
        for (int t = 0; t < 4; ++t) {
          const bool p = vv[t] > thr;
          const unsigned long long bal = __ballot(p);
          if (bal) {
            int base = 0;
            if (lane == 0) base = atomicAdd(&s_cnt, __popcll(bal));
            base = __shfl(base, 0);
            if (p) {
              const int off = base + __popcll(bal & ((1ull << lane) - 1ull));
              if (off < CCAP) cand[off] = vv[t];
            }
          }
        }
      }
      __syncthreads();                   // barrier 2 (the last one in hot path)
      const int c = s_cnt;               // captured immediately by every wave

      float tau;                         // raw-space threshold, per-wave register
      if (c <= 64) {
        // ---- exact solve, executed redundantly by ALL FOUR waves ----
        const float v = (lane < c) ? cand[lane] : 0.0f;
        int rank = 0;
        for (int q = 0; q < c; ++q) {    // all-pairs rank via shfl broadcast
          const float t = __shfl(v, q);
          rank += (t > v) || (t == v && q < lane);
        }
        if (lane < c) sorted[w][rank] = v;        // own row; in-wave LDS, no barrier
        const float sv = (lane < c) ? sorted[w][lane] : 0.0f;
        float cs = sv;
#pragma unroll
        for (int o = 1; o < 64; o <<= 1) {        // inclusive prefix scan
          const float t2 = __shfl_up(cs, o);
          if (lane >= o) cs += t2;
        }
        const int flag = (lane < c) && (sv * (float)(lane + 1) > cs - 1.0f);
        const unsigned long long bal2 = __ballot(flag);  // lane 0 always true
        const int k = 63 - __clzll(bal2);                // support size - 1
        const float csk = __shfl(cs, k);
        tau = (csk - 1.0f) / (float)(k + 1);             // identical in all waves
      } else if (c <= CCAP) {
        // ---- redundant per-wave Michelot over LDS candidates ----
        tau = thr;                       // tau0 = gmax-1 <= tau*
        int cnt = -1;
        for (int it = 0; it < 64; ++it) {
          float s2 = 0.0f; int c2 = 0;
          for (int q = lane; q < c; q += 64) {
            const float vv = cand[q];
            if (vv > tau) { s2 += vv; c2++; }
          }
          s2 = wave_sum(s2); c2 = wave_sum_i(c2);
          if (c2 == cnt || c2 == 0) break;
          tau = (s2 - 1.0f) / (float)c2; cnt = c2;
        }
      } else {
        // ---- pathological overflow: block Michelot on registers ----
        tau = thr;
        int cnt = -1;
        for (int it = 0; it < 64; ++it) {
          float s2 = 0.0f; int c2 = 0;
#pragma unroll
          for (int j = 0; j < QPT; ++j) {
            const float vv[4] = {r[j].x, r[j].y, r[j].z, r[j].w};
#pragma unroll
            for (int t = 0; t < 4; ++t)
              if (vv[t] > tau) { s2 += vv[t]; c2++; }   // -inf never passes
          }
          block_sum_cnt(s2, c2, redf, redi, tid);       // block-uniform barriers
          if (c2 == cnt || c2 == 0) break;
          tau = (s2 - 1.0f) / (float)c2; cnt = c2;
        }
        if (tid == 0) s_tau = tau;
        __syncthreads();
        tau = s_tau;
      }

      // ---- phase 3: store with per-wave tau (no barrier needed) ----
#pragma unroll
      for (int j = 0; j < QPT; ++j) {
        const int idx = a0 + (j * BLK + tid) * 4;
        if (idx >= e) continue;
        if (idx >= s && idx + 4 <= e) {
          float4 o4;
          o4.x = fmaxf(r[j].x - tau, 0.0f);
          o4.y = fmaxf(r[j].y - tau, 0.0f);
          o4.z = fmaxf(r[j].z - tau, 0.0f);
          o4.w = fmaxf(r[j].w - tau, 0.0f);
          *(float4*)(out + idx) = o4;
        } else {
          const float vv[4] = {r[j].x, r[j].y, r[j].z, r[j].w};
#pragma unroll
          for (int t = 0; t < 4; ++t) {
            const int p2 = idx + t;
            if (p2 >= s && p2 < e) out[p2] = fmaxf(vv[t] - tau, 0.0f);
          }
        }
      }
    } else {
      // ---- n > capacity fallback: block-strided global Michelot ----
      float gmax = -INFINITY;
      for (int i = s + tid; i < e; i += BLK) gmax = fmaxf(gmax, x[i]);
      gmax = wave_max(gmax);
      if (lane == 0) redf[w] = gmax;
      __syncthreads();
      gmax = fmaxf(fmaxf(redf[0], redf[1]), fmaxf(redf[2], redf[3]));
      float tau = gmax - 1.0f;
      int cnt = -1;
      for (int it = 0; it < 64; ++it) {
        float s2 = 0.0f; int c2 = 0;
        for (int i = s + tid; i < e; i += BLK) {
          const float vs = x[i];
          if (vs > tau) { s2 += vs; c2++; }
        }
        block_sum_cnt(s2, c2, redf, redi, tid);
        if (c2 == cnt || c2 == 0) break;
        tau = (s2 - 1.0f) / (float)c2; cnt = c2;
      }
      for (int i = s + tid; i < e; i += BLK) out[i] = fmaxf(x[i] - tau, 0.0f);
    }
  }
}

extern "C" void kernel_launch(void* const* d_in, const int* in_sizes, int n_in,
                              void* d_out, int out_size, void* d_ws, size_t ws_size,
                              hipStream_t stream) {
  const float* x     = (const float*)d_in[0];
  const int*   batch = (const int*)d_in[1];   // int32 on device (JAX x64 disabled)
  const int*   pB    = (const int*)d_in[2];
  float*       out   = (float*)d_out;
  const int N = in_sizes[0];

  int* starts = (int*)d_ws;                    // 4*(B+1) bytes of scratch

  // kernel1: 1025 blocks x 4 waves = 4100 waves >= 4097 boundaries
  build_starts_bs<<<dim3(1025), dim3(BLK), 0, stream>>>(batch, starts, pB, N);
  // kernel2: 2048 blocks = 8/CU exactly; each block handles 2 groups
  sparsemax_groups<<<dim3(2048), dim3(BLK), 0, stream>>>(x, starts, pB, out, N);
}

// Round 10
// 111.455 us; speedup vs baseline: 1.0572x; 1.0357x over previous
//
#include <hip/hip_runtime.h>

#define BLK 256
#define QPT 3                   // float4 per thread -> 3072-element capacity per block
#define CAPB (QPT * BLK * 4)    // 3072
#define CCAP 320                // candidate buffer: c<=64 exact; <=CCAP wave-Michelot; else block Michelot

// ---------- wave-local reductions (64-lane) ----------

__device__ __forceinline__ float wave_max(float v) {
#pragma unroll
  for (int o = 32; o; o >>= 1) v = fmaxf(v, __shfl_xor(v, o));
  return v;
}
__device__ __forceinline__ float wave_sum(float v) {
#pragma unroll
  for (int o = 32; o; o >>= 1) v += __shfl_xor(v, o);
  return v;
}
__device__ __forceinline__ int wave_sum_i(int v) {
#pragma unroll
  for (int o = 32; o; o >>= 1) v += __shfl_xor(v, o);
  return v;
}

__device__ __forceinline__ void block_sum_cnt(float& s, int& c, float* redf, int* redi, int tid) {
  s = wave_sum(s); c = wave_sum_i(c);
  __syncthreads();
  if ((tid & 63) == 0) { redf[tid >> 6] = s; redi[tid >> 6] = c; }
  __syncthreads();
  s = redf[0] + redf[1] + redf[2] + redf[3];
  c = redi[0] + redi[1] + redi[2] + redi[3];
}

// ---------- kernel 1: boundary detect -> starts[0..B], int4-vectorized ----------
// Coalesced stream of the whole batch array. Measured better than the
// 65-ary wave-search variant (R5 112.4 vs R7/R8/R9 114-118): the search's
// per-round 64-line gather costs more than this fully-coalesced stream.

extern "C" __global__ void __launch_bounds__(256)
build_starts(const int* __restrict__ batch, int* __restrict__ starts,
             const int* __restrict__ pB, int N) {
  const int B = *pB;
  const long long tid = (long long)blockIdx.x * 256 + threadIdx.x;
  const long long i0 = tid * 8;
  if (i0 >= N) return;
  int v[8];
  if (i0 + 8 <= N) {
    const int4 a = *(const int4*)(batch + i0);
    const int4 b = *(const int4*)(batch + i0 + 4);
    v[0] = a.x; v[1] = a.y; v[2] = a.z; v[3] = a.w;
    v[4] = b.x; v[5] = b.y; v[6] = b.z; v[7] = b.w;
  } else {
#pragma unroll
    for (int t = 0; t < 8; ++t) v[t] = (i0 + t < N) ? batch[i0 + t] : 0;
  }
  int prev = (i0 == 0) ? -1 : batch[i0 - 1];   // same cacheline as neighbor: L1 hit
#pragma unroll
  for (int t = 0; t < 8; ++t) {
    if (i0 + t >= N) break;
    const int cur = v[t];
    for (int g = prev + 1; g <= cur; ++g) starts[g] = (int)(i0 + t);
    prev = cur;
  }
  if (i0 + 8 >= N) {
    for (int g = prev + 1; g <= B; ++g) starts[g] = N;
  }
}

// ---------- kernel 2: one BLOCK (4 waves) per group, 3 barriers ----------
// tau >= -1 bound (outputs sum to 1) => support subset of {x > gmax-1};
// ballot-compact (~25 cands for Gaussian n=2048) into LDS, exact rank-sort
// + shfl prefix-scan + ballot solve on wave 0. Payload stays in registers.

extern "C" __global__ void __launch_bounds__(BLK)
sparsemax_groups(const float* __restrict__ x, const int* __restrict__ starts,
                 const int* __restrict__ pB, float* __restrict__ out, int N) {
  __shared__ float redf[4];
  __shared__ int   redi[4];
  __shared__ float cand[CCAP];
  __shared__ float sorted[64];
  __shared__ int   s_cnt;
  __shared__ float s_csum;
  __shared__ float s_tau;
  const int tid  = threadIdx.x;
  const int lane = tid & 63;
  const int w    = tid >> 6;
  const int B = *pB;

  for (int g = blockIdx.x; g < B; g += gridDim.x) {
    const int s = starts[g];
    const int e = starts[g + 1];
    const int n = e - s;
    if (n <= 0) continue;
    const int a0 = s & ~3;               // 16B-aligned load base

    if (e - a0 <= CAPB) {
      // ---- phase 1: aligned float4 global -> registers, fused max ----
      float4 r[QPT];
      float lmax = -INFINITY;
#pragma unroll
      for (int j = 0; j < QPT; ++j) {
        const int idx = a0 + (j * BLK + tid) * 4;
        float4 v = make_float4(-INFINITY, -INFINITY, -INFINITY, -INFINITY);
        if (idx < e) {
          if (idx + 4 <= N) {
            v = *(const float4*)(x + idx);
          } else {                        // buffer tail (last group only)
            if (idx + 0 < N) v.x = x[idx + 0];
            if (idx + 1 < N) v.y = x[idx + 1];
            if (idx + 2 < N) v.z = x[idx + 2];
            if (idx + 3 < N) v.w = x[idx + 3];
          }
          if (idx + 0 < s || idx + 0 >= e) v.x = -INFINITY;  // mask other groups
          if (idx + 1 < s || idx + 1 >= e) v.y = -INFINITY;
          if (idx + 2 < s || idx + 2 >= e) v.z = -INFINITY;
          if (idx + 3 < s || idx + 3 >= e) v.w = -INFINITY;
        }
        r[j] = v;
        lmax = fmaxf(lmax, fmaxf(fmaxf(v.x, v.y), fmaxf(v.z, v.w)));
      }
      lmax = wave_max(lmax);
      if (lane == 0) redf[w] = lmax;
      if (tid == 0) { s_cnt = 0; s_csum = 0.0f; }
      __syncthreads();                   // barrier 1
      const float gmax = fmaxf(fmaxf(redf[0], redf[1]), fmaxf(redf[2], redf[3]));
      const float thr = gmax - 1.0f;

      // ---- phase 2: ballot compaction, ONE LDS atomic per wave per component ----
      float wsum = 0.0f;                 // this lane's candidate sum (shifted)
#pragma unroll
      for (int j = 0; j < QPT; ++j) {
        const float vv[4] = {r[j].x, r[j].y, r[j].z, r[j].w};
#pragma unroll
        for (int t = 0; t < 4; ++t) {
          const bool p = vv[t] > thr;
          const unsigned long long bal = __ballot(p);
          if (bal) {
            int base = 0;
            if (lane == 0) base = atomicAdd(&s_cnt, __popcll(bal));
            base = __shfl(base, 0);
            if (p) {
              const int off = base + __popcll(bal & ((1ull << lane) - 1ull));
              if (off < CCAP) cand[off] = vv[t];
              wsum += vv[t] - gmax;
            }
          }
        }
      }
      wsum = wave_sum(wsum);
      if (lane == 0) atomicAdd(&s_csum, wsum);
      __syncthreads();                   // barrier 2
      const int c = s_cnt;               // >= 1 (max element always passes)

      if (c <= 64) {
        if (w == 0) {                    // exact solve on wave 0
          const float v = (lane < c) ? cand[lane] - gmax : 0.0f;
          int rank = 0;
          for (int q = 0; q < c; ++q) {
            const float t = cand[q] - gmax;
            rank += (t > v) || (t == v && q < lane);  // unique ranks
          }
          if (lane < c) sorted[rank] = v;             // sorted[0] == 0
          const float sv = (lane < c) ? sorted[lane] : 0.0f;
          float cs = sv;
#pragma unroll
          for (int o = 1; o < 64; o <<= 1) {          // inclusive prefix scan
            const float t2 = __shfl_up(cs, o);
            if (lane >= o) cs += t2;
          }
          const int flag = (lane < c) && (sv * (float)(lane + 1) > cs - 1.0f);
          const unsigned long long bal2 = __ballot(flag);  // lane 0 always true
          const int k = 63 - __clzll(bal2);                // support size - 1
          const float csk = __shfl(cs, k);
          if (lane == 0) s_tau = (csk - 1.0f) / (float)(k + 1);
        }
      } else if (c <= CCAP) {
        if (w == 0) {                    // wave-0 Michelot over LDS candidates
          float tau = (s_csum - 1.0f) / (float)c;
          int cnt = c;
          for (int it = 0; it < 64; ++it) {
            float s2 = 0.0f; int c2 = 0;
            for (int q = lane; q < c; q += 64) {
              const float vs = cand[q] - gmax;
              if (vs > tau) { s2 += vs; c2++; }
            }
            s2 = wave_sum(s2); c2 = wave_sum_i(c2);
            if (c2 == cnt || c2 == 0) break;
            tau = (s2 - 1.0f) / (float)c2; cnt = c2;
          }
          if (lane == 0) s_tau = tau;
        }
      } else {
        // block-uniform pathological path: Michelot on registers (has barriers)
        float tau = (s_csum - 1.0f) / (float)c;
        int cnt = c;
        for (int it = 0; it < 64; ++it) {
          float s2 = 0.0f; int c2 = 0;
#pragma unroll
          for (int j = 0; j < QPT; ++j) {
            const float vv[4] = {r[j].x, r[j].y, r[j].z, r[j].w};
#pragma unroll
            for (int t = 0; t < 4; ++t) {
              const float vs = vv[t] - gmax;            // -inf never passes
              if (vs > tau) { s2 += vs; c2++; }
            }
          }
          block_sum_cnt(s2, c2, redf, redi, tid);
          if (c2 == cnt || c2 == 0) break;
          tau = (s2 - 1.0f) / (float)c2; cnt = c2;
        }
        if (tid == 0) s_tau = tau;
      }
      __syncthreads();                   // barrier 3
      const float sub = s_tau + gmax;    // unshifted threshold

      // ---- phase 3: store (vector interior, scalar boundary quads) ----
#pragma unroll
      for (int j = 0; j < QPT; ++j) {
        const int idx = a0 + (j * BLK + tid) * 4;
        if (idx >= e) continue;
        if (idx >= s && idx + 4 <= e) {
          float4 o4;
          o4.x = fmaxf(r[j].x - sub, 0.0f);
          o4.y = fmaxf(r[j].y - sub, 0.0f);
          o4.z = fmaxf(r[j].z - sub, 0.0f);
          o4.w = fmaxf(r[j].w - sub, 0.0f);
          *(float4*)(out + idx) = o4;
        } else {
          const float vv[4] = {r[j].x, r[j].y, r[j].z, r[j].w};
#pragma unroll
          for (int t = 0; t < 4; ++t) {
            const int p2 = idx + t;
            if (p2 >= s && p2 < e) out[p2] = fmaxf(vv[t] - sub, 0.0f);
          }
        }
      }
    } else {
      // ---- n > capacity fallback: block-strided global Michelot ----
      float gmax = -INFINITY;
      for (int i = s + tid; i < e; i += BLK) gmax = fmaxf(gmax, x[i]);
      gmax = wave_max(gmax);
      if (lane == 0) redf[w] = gmax;
      __syncthreads();
      gmax = fmaxf(fmaxf(redf[0], redf[1]), fmaxf(redf[2], redf[3]));
      float bs = 0.0f; int bc = 0;
      for (int i = s + tid; i < e; i += BLK) {
        const float vs = x[i] - gmax;
        if (vs > -1.0f) { bs += vs; bc++; }
      }
      block_sum_cnt(bs, bc, redf, redi, tid);
      float tau = (bs - 1.0f) / (float)bc;
      int cntS = bc;
      for (int it = 0; it < 64; ++it) {
        float s2 = 0.0f; int c2 = 0;
        for (int i = s + tid; i < e; i += BLK) {
          const float vs = x[i] - gmax;
          if (vs > tau) { s2 += vs; c2++; }
        }
        block_sum_cnt(s2, c2, redf, redi, tid);
        if (c2 == cntS || c2 == 0) break;
        tau = (s2 - 1.0f) / (float)c2; cntS = c2;
      }
      const float sub = tau + gmax;
      for (int i = s + tid; i < e; i += BLK) out[i] = fmaxf(x[i] - sub, 0.0f);
    }
  }
}

extern "C" void kernel_launch(void* const* d_in, const int* in_sizes, int n_in,
                              void* d_out, int out_size, void* d_ws, size_t ws_size,
                              hipStream_t stream) {
  const float* x     = (const float*)d_in[0];
  const int*   batch = (const int*)d_in[1];   // int32 on device (JAX x64 disabled)
  const int*   pB    = (const int*)d_in[2];
  float*       out   = (float*)d_out;
  const int N = in_sizes[0];

  int* starts = (int*)d_ws;                    // 4*(B+1) bytes of scratch

  const int g1 = (N + 2047) / 2048;            // 8 elems/thread, 256 threads
  build_starts<<<dim3(g1), dim3(256), 0, stream>>>(batch, starts, pB, N);
  // one block (4 waves) per group; grid-strides if B > 4096
  sparsemax_groups<<<dim3(4096), dim3(BLK), 0, stream>>>(x, starts, pB, out, N);
}